// Round 3
// baseline (2478.996 us; speedup 1.0000x reference)
//
#include <hip/hip_runtime.h>

// ---------------- problem dims ----------------
#define TT   512
#define DIN  1024
#define DH   2048
#define DOUT 1024

// ---------------- launch shape ----------------
#define NWG   256    // WGs 0..127: h1 chain (+epilogue); 128..255: h2 chain
#define HALF  128
#define NTHR  512    // 8 waves; each wave owns 2 h-rows of its chain
#define NSLOT (TT + 1)

typedef unsigned int u32;
typedef unsigned long long u64;

// Records: one u64 per h element per step {epoch (hi 32) | f32 bits (lo 32)}.
// A single u64 relaxed agent-scope store/load is architecturally atomic ->
// data and readiness travel in ONE L3 round trip (no separate flag hop —
// round 2's flag scheme added 2 serial hops and regressed; reverted).
// Slot t is unique per step -> no ring reuse, no ABA, deadlock-free DAG.
//
// POLL DISCIPLINE (the round-3 fix): every retry round is issue-phase then
// check-phase. Loads are unconditional instructions with a branchless
// address select (done lanes re-read the slot base -> coalesce to one hot
// line), so the compiler cannot fold load+check into one guarded block and
// serialize the waits. One L3 RT per round, pending-only traffic.
__device__ u64 gR1[NSLOT * DH];   // h1 records
__device__ u64 gR2[NSLOT * DH];   // h2 records
__device__ u32 g_epoch_base;      // zero at module load; +=NSLOT per run

__device__ __forceinline__ float dot4(float4 a, float4 b) {
  return a.x * b.x + a.y * b.y + a.z * b.z + a.w * b.w;
}
// xor-butterfly: ALL lanes end with the sum (lets lane 0 and lane 1 publish
// the two rows in parallel instead of lane 0 doing both serially).
__device__ __forceinline__ float wave_sum_all(float v) {
  #pragma unroll
  for (int m = 32; m > 0; m >>= 1) v += __shfl_xor(v, m, 64);
  return v;
}
__device__ __forceinline__ u64 ld_rec(const u64* p) {
  return __hip_atomic_load((u64*)p, __ATOMIC_RELAXED, __HIP_MEMORY_SCOPE_AGENT);
}
__device__ __forceinline__ void st_rec(u64* p, u64 v) {
  __hip_atomic_store(p, v, __ATOMIC_RELAXED, __HIP_MEMORY_SCOPE_AGENT);
}
__device__ __forceinline__ u64 pack(float h, u32 ep) {
  return ((u64)ep << 32) | (u64)__float_as_uint(h);
}
__device__ __forceinline__ bool chk(u64 v, u32 ep) {
  return (u32)(v >> 32) == ep;
}
// Fast tanh, ~3 ulp, branch-free: only lanes 0/1 (2x per wave per step).
__device__ __forceinline__ float fast_tanh(float x) {
  float xc = fminf(fmaxf(x, -9.0f), 9.0f);
  float e  = __expf(2.0f * xc);
  return (e - 1.0f) * __frcp_rn(e + 1.0f);
}

// One poll round, single slot: issue 4 loads (branchless addr select keeps
// done lanes on the coalesced slot base), then check with one wait chain.
// Thread tid watches records {tid, tid+512, tid+1024, tid+1536}.
__device__ __forceinline__ void poll_stage(const u64* rec, u32 ep,
                                           float* lds, int tid) {
  const u64 *p0 = rec + tid, *p1 = rec + tid + NTHR,
            *p2 = rec + tid + 2 * NTHR, *p3 = rec + tid + 3 * NTHR;
  u64 v0 = 0, v1 = 0, v2 = 0, v3 = 0;
  bool d0 = false, d1 = false, d2 = false, d3 = false;
  for (;;) {
    // issue phase — 4 back-to-back loads, no intervening waits
    u64 t0 = ld_rec(d0 ? rec : p0);
    u64 t1 = ld_rec(d1 ? rec : p1);
    u64 t2 = ld_rec(d2 ? rec : p2);
    u64 t3 = ld_rec(d3 ? rec : p3);
    // check phase — progressive vmcnt waits, ~one RT total
    if (!d0 && chk(t0, ep)) { v0 = t0; d0 = true; }
    if (!d1 && chk(t1, ep)) { v1 = t1; d1 = true; }
    if (!d2 && chk(t2, ep)) { v2 = t2; d2 = true; }
    if (!d3 && chk(t3, ep)) { v3 = t3; d3 = true; }
    if (d0 & d1 & d2 & d3) break;
    __builtin_amdgcn_s_sleep(1);
  }
  lds[tid           ] = __uint_as_float((u32)v0);
  lds[tid +     NTHR] = __uint_as_float((u32)v1);
  lds[tid + 2 * NTHR] = __uint_as_float((u32)v2);
  lds[tid + 3 * NTHR] = __uint_as_float((u32)v3);
}

// Dual-slot variant (h2 chain: h1[t] and h2[t-1]) — 8 issues, one wait chain.
__device__ __forceinline__ void poll_stage2(const u64* recA, u32 epA,
                                            const u64* recB, u32 epB,
                                            float* ldsA, float* ldsB, int tid) {
  const u64 *pa0 = recA + tid, *pa1 = recA + tid + NTHR,
            *pa2 = recA + tid + 2 * NTHR, *pa3 = recA + tid + 3 * NTHR;
  const u64 *pb0 = recB + tid, *pb1 = recB + tid + NTHR,
            *pb2 = recB + tid + 2 * NTHR, *pb3 = recB + tid + 3 * NTHR;
  u64 a0 = 0, a1 = 0, a2 = 0, a3 = 0, b0 = 0, b1 = 0, b2 = 0, b3 = 0;
  bool da0 = false, da1 = false, da2 = false, da3 = false;
  bool db0 = false, db1 = false, db2 = false, db3 = false;
  for (;;) {
    u64 ta0 = ld_rec(da0 ? recA : pa0);
    u64 ta1 = ld_rec(da1 ? recA : pa1);
    u64 ta2 = ld_rec(da2 ? recA : pa2);
    u64 ta3 = ld_rec(da3 ? recA : pa3);
    u64 tb0 = ld_rec(db0 ? recB : pb0);
    u64 tb1 = ld_rec(db1 ? recB : pb1);
    u64 tb2 = ld_rec(db2 ? recB : pb2);
    u64 tb3 = ld_rec(db3 ? recB : pb3);
    if (!da0 && chk(ta0, epA)) { a0 = ta0; da0 = true; }
    if (!da1 && chk(ta1, epA)) { a1 = ta1; da1 = true; }
    if (!da2 && chk(ta2, epA)) { a2 = ta2; da2 = true; }
    if (!da3 && chk(ta3, epA)) { a3 = ta3; da3 = true; }
    if (!db0 && chk(tb0, epB)) { b0 = tb0; db0 = true; }
    if (!db1 && chk(tb1, epB)) { b1 = tb1; db1 = true; }
    if (!db2 && chk(tb2, epB)) { b2 = tb2; db2 = true; }
    if (!db3 && chk(tb3, epB)) { b3 = tb3; db3 = true; }
    if (da0 & da1 & da2 & da3 & db0 & db1 & db2 & db3) break;
    __builtin_amdgcn_s_sleep(1);
  }
  ldsA[tid           ] = __uint_as_float((u32)a0);
  ldsA[tid +     NTHR] = __uint_as_float((u32)a1);
  ldsA[tid + 2 * NTHR] = __uint_as_float((u32)a2);
  ldsA[tid + 3 * NTHR] = __uint_as_float((u32)a3);
  ldsB[tid           ] = __uint_as_float((u32)b0);
  ldsB[tid +     NTHR] = __uint_as_float((u32)b1);
  ldsB[tid + 2 * NTHR] = __uint_as_float((u32)b2);
  ldsB[tid + 3 * NTHR] = __uint_as_float((u32)b3);
}

// Advance the epoch base past all epochs any previous run could have stored.
__global__ void bump_kernel() {
  if (threadIdx.x == 0)
    __hip_atomic_fetch_add(&g_epoch_base, (u32)NSLOT,
                           __ATOMIC_RELAXED, __HIP_MEMORY_SCOPE_AGENT);
}

__global__ __launch_bounds__(NTHR, 2)
void rnn2_kernel(const float* __restrict__ X,
                 const float* __restrict__ Wa, const float* __restrict__ ba,
                 const float* __restrict__ Wb, const float* __restrict__ bb,
                 const float* __restrict__ Wc, const float* __restrict__ bc,
                 const float* __restrict__ Wd, const float* __restrict__ bd,
                 const float* __restrict__ Wo, const float* __restrict__ bo,
                 float* __restrict__ out)
{
  const int g   = blockIdx.x;
  const int tid = threadIdx.x;
  const int w   = tid >> 6;   // wave
  const int l   = tid & 63;   // lane

  const u32 eb = __hip_atomic_load(&g_epoch_base, __ATOMIC_RELAXED,
                                   __HIP_MEMORY_SCOPE_AGENT);

  // Double-buffered staging: stage(t) writes parity (t-1)&1 [h1] / t&1 [h2];
  // one barrier per step between stage and dot bounds wave skew -> reuse of
  // a parity buffer two steps later is race-free.
  __shared__ float sA[2][DH];
  __shared__ float sB[2][DH];

  if (g < HALF) {
    // ================= h1 chain (+ output epilogue) =================
    const int r0 = g * 16 + 2 * w, r1 = r0 + 1;   // my two h1 rows
    float4 wA0[4], wA1[4], wB0[8], wB1[8], wO[8];
    {
      const float4* p0 = (const float4*)(Wa + (size_t)r0 * DIN);
      const float4* p1 = (const float4*)(Wa + (size_t)r1 * DIN);
      #pragma unroll
      for (int j = 0; j < 4; ++j) { wA0[j] = p0[l + 64 * j]; wA1[j] = p1[l + 64 * j]; }
    }
    {
      const float4* p0 = (const float4*)(Wb + (size_t)r0 * DH);
      const float4* p1 = (const float4*)(Wb + (size_t)r1 * DH);
      #pragma unroll
      for (int j = 0; j < 8; ++j) { wB0[j] = p0[l + 64 * j]; wB1[j] = p1[l + 64 * j]; }
    }
    const int orow = g * 8 + w;                   // my output row
    {
      const float4* p = (const float4*)(Wo + (size_t)orow * DH);
      #pragma unroll
      for (int j = 0; j < 8; ++j) wO[j] = p[l + 64 * j];
    }
    const float b1_0 = ba[r0] + bb[r0];
    const float b1_1 = ba[r1] + bb[r1];
    const float bo_r = bo[orow];

    for (int t = 1; t <= TT; ++t) {
      const u32 epp = eb + (u32)(t - 1);
      const u64* pr = gR1 + (size_t)(t - 1) * DH;

      // Pre-issue poll round 0 BEFORE the X-dot: its RT hides under the
      // ~200 cycles of independent X.Wa work below.
      u64 t0 = 0, t1 = 0, t2 = 0, t3 = 0;
      if (t > 1) {
        t0 = ld_rec(pr + tid);
        t1 = ld_rec(pr + tid + NTHR);
        t2 = ld_rec(pr + tid + 2 * NTHR);
        t3 = ld_rec(pr + tid + 3 * NTHR);
      }

      // A.x[t-1]: no cross-WG dependency
      float a0 = 0.f, a1 = 0.f;
      {
        const float4* px = (const float4*)(X + (size_t)(t - 1) * DIN);
        #pragma unroll
        for (int j = 0; j < 4; ++j) {
          float4 x4 = px[l + 64 * j];
          a0 += dot4(wA0[j], x4);
          a1 += dot4(wA1[j], x4);
        }
      }

      if (t > 1) {
        float* buf = sA[(t - 1) & 1];
        // check pre-issued round, then fall into issue/check rounds
        u64 v0 = 0, v1 = 0, v2 = 0, v3 = 0;
        bool d0 = chk(t0, epp), d1 = chk(t1, epp),
             d2 = chk(t2, epp), d3 = chk(t3, epp);
        if (d0) v0 = t0;
        if (d1) v1 = t1;
        if (d2) v2 = t2;
        if (d3) v3 = t3;
        while (!(d0 & d1 & d2 & d3)) {
          __builtin_amdgcn_s_sleep(1);
          u64 u0 = ld_rec(d0 ? pr : pr + tid);
          u64 u1 = ld_rec(d1 ? pr : pr + tid + NTHR);
          u64 u2 = ld_rec(d2 ? pr : pr + tid + 2 * NTHR);
          u64 u3 = ld_rec(d3 ? pr : pr + tid + 3 * NTHR);
          if (!d0 && chk(u0, epp)) { v0 = u0; d0 = true; }
          if (!d1 && chk(u1, epp)) { v1 = u1; d1 = true; }
          if (!d2 && chk(u2, epp)) { v2 = u2; d2 = true; }
          if (!d3 && chk(u3, epp)) { v3 = u3; d3 = true; }
        }
        buf[tid           ] = __uint_as_float((u32)v0);
        buf[tid +     NTHR] = __uint_as_float((u32)v1);
        buf[tid + 2 * NTHR] = __uint_as_float((u32)v2);
        buf[tid + 3 * NTHR] = __uint_as_float((u32)v3);
        __syncthreads();
        const float4* ph = (const float4*)buf;
        #pragma unroll
        for (int j = 0; j < 8; ++j) {
          float4 h4 = ph[l + 64 * j];
          a0 += dot4(wB0[j], h4);
          a1 += dot4(wB1[j], h4);
        }
      }
      a0 = wave_sum_all(a0); a1 = wave_sum_all(a1);
      {   // publish: lanes 0 and 1 store the two rows in parallel
        const u32 ept = eb + (u32)t;
        u64* dst = gR1 + (size_t)t * DH;
        if (l == 0) st_rec(dst + r0, pack(fast_tanh(a0 + b1_0), ept));
        if (l == 1) st_rec(dst + r1, pack(fast_tanh(a1 + b1_1), ept));
      }
    }

    // ---- epilogue: out = Wo . h2[TT] + bo (1 row per wave) ----
    // sA[0] parity != the loop's last dot buffer (sA[1]) -> race-free.
    poll_stage(gR2 + (size_t)TT * DH, eb + (u32)TT, sA[0], tid);
    __syncthreads();
    {
      const float4* ph = (const float4*)sA[0];
      float acc = 0.f;
      #pragma unroll
      for (int j = 0; j < 8; ++j) acc += dot4(wO[j], ph[l + 64 * j]);
      acc = wave_sum_all(acc);
      if (l == 0) out[orow] = acc + bo_r;
    }
  } else {
    // ========================= h2 chain =========================
    const int gg = g - HALF;
    const int r0 = gg * 16 + 2 * w, r1 = r0 + 1;  // my two h2 rows
    float4 wC0[8], wC1[8], wD0[8], wD1[8];
    {
      const float4* p0 = (const float4*)(Wc + (size_t)r0 * DH);
      const float4* p1 = (const float4*)(Wc + (size_t)r1 * DH);
      #pragma unroll
      for (int j = 0; j < 8; ++j) { wC0[j] = p0[l + 64 * j]; wC1[j] = p1[l + 64 * j]; }
    }
    {
      const float4* p0 = (const float4*)(Wd + (size_t)r0 * DH);
      const float4* p1 = (const float4*)(Wd + (size_t)r1 * DH);
      #pragma unroll
      for (int j = 0; j < 8; ++j) { wD0[j] = p0[l + 64 * j]; wD1[j] = p1[l + 64 * j]; }
    }
    const float b2_0 = bc[r0] + bd[r0];
    const float b2_1 = bc[r1] + bd[r1];

    for (int t = 1; t <= TT; ++t) {
      float* bufA = sA[t & 1];
      float* bufB = sB[t & 1];
      const u32 ept = eb + (u32)t;
      if (t > 1)
        poll_stage2(gR1 + (size_t)t * DH, ept,
                    gR2 + (size_t)(t - 1) * DH, eb + (u32)(t - 1), bufA, bufB, tid);
      else
        poll_stage(gR1 + (size_t)1 * DH, eb + 1u, bufA, tid);
      __syncthreads();

      float a0 = 0.f, a1 = 0.f;
      {
        const float4* ph = (const float4*)bufA;
        #pragma unroll
        for (int j = 0; j < 8; ++j) {
          float4 h4 = ph[l + 64 * j];
          a0 += dot4(wC0[j], h4);
          a1 += dot4(wC1[j], h4);
        }
      }
      if (t > 1) {
        const float4* ph = (const float4*)bufB;
        #pragma unroll
        for (int j = 0; j < 8; ++j) {
          float4 h4 = ph[l + 64 * j];
          a0 += dot4(wD0[j], h4);
          a1 += dot4(wD1[j], h4);
        }
      }
      a0 = wave_sum_all(a0); a1 = wave_sum_all(a1);
      {
        u64* dst = gR2 + (size_t)t * DH;
        if (l == 0) st_rec(dst + r0, pack(fast_tanh(a0 + b2_0), ept));
        if (l == 1) st_rec(dst + r1, pack(fast_tanh(a1 + b2_1), ept));
      }
    }
  }
}

extern "C" void kernel_launch(void* const* d_in, const int* in_sizes, int n_in,
                              void* d_out, int out_size, void* d_ws, size_t ws_size,
                              hipStream_t stream)
{
  (void)in_sizes; (void)n_in; (void)out_size; (void)d_ws; (void)ws_size;

  const float* X  = (const float*)d_in[0];
  const float* Wa = (const float*)d_in[1];   // W_i2h1 [H][IN]
  const float* ba = (const float*)d_in[2];
  const float* Wb = (const float*)d_in[3];   // W_h2h1 [H][H]
  const float* bb = (const float*)d_in[4];
  // d_in[5], d_in[6]: W_h2o1 / b_h2o1 — dead code in the reference
  const float* Wc = (const float*)d_in[7];   // W_i2h2 [H][H]
  const float* bc = (const float*)d_in[8];
  const float* Wd = (const float*)d_in[9];   // W_h2h2 [H][H]
  const float* bd = (const float*)d_in[10];
  const float* Wo = (const float*)d_in[11];  // W_h2o2 [OUT][H]
  const float* bo = (const float*)d_in[12];
  float* out = (float*)d_out;

  bump_kernel<<<dim3(1), dim3(64), 0, stream>>>();

  void* args[] = { &X, &Wa, &ba, &Wb, &bb, &Wc, &bc, &Wd, &bd, &Wo, &bo, &out };
  (void)hipLaunchCooperativeKernel((void*)rnn2_kernel, dim3(NWG), dim3(NTHR),
                                   args, 0, stream);
}

// Round 4
// 1593.994 us; speedup vs baseline: 1.5552x; 1.5552x over previous
//
#include <hip/hip_runtime.h>

// ---------------- problem dims ----------------
#define TT   512
#define DIN  1024
#define DH   2048
#define DOUT 1024

// ---------------- launch shape ----------------
#define NWG   256    // WGs 0..127: h1 chain (+epilogue); 128..255: h2 chain
#define HALF  128
#define NTHR  512    // 8 waves; each wave owns 2 h-rows of its chain
#define NSLOT (TT + 1)

typedef unsigned int u32;
typedef unsigned long long u64;

// Records are now ONE u32 each: the f32 bits of h. Readiness is encoded by
// value: SENT (0xFFFFFFFF, a NaN bit pattern) = empty; tanh output can never
// be NaN, so any non-SENT value is ready data. Data + readiness still travel
// in a single architecturally-atomic load — same one-RT property as the u64
// epoch records, at HALF the poll bytes per round (hot slot 16KB -> 8KB,
// 128 -> 64 L3 lines). R0/R3 established period ~ poll-round bytes, so this
// is a direct cut of the dominant term with zero protocol change.
// Cost: sentinel re-init per run (8.4 MB, ~5-10us, stream-serialized).
#define SENT 0xFFFFFFFFu
__device__ u32 gR1[NSLOT * DH];   // h1 records
__device__ u32 gR2[NSLOT * DH];   // h2 records

__device__ __forceinline__ float dot4(float4 a, float4 b) {
  return a.x * b.x + a.y * b.y + a.z * b.z + a.w * b.w;
}
__device__ __forceinline__ float wave_sum(float v) {
  #pragma unroll
  for (int off = 32; off > 0; off >>= 1) v += __shfl_down(v, off, 64);
  return v; // lane 0 holds the sum
}
__device__ __forceinline__ u32 ld_rec(const u32* p) {
  return __hip_atomic_load((u32*)p, __ATOMIC_RELAXED, __HIP_MEMORY_SCOPE_AGENT);
}
__device__ __forceinline__ void st_rec(u32* p, u32 v) {
  __hip_atomic_store(p, v, __ATOMIC_RELAXED, __HIP_MEMORY_SCOPE_AGENT);
}
// Fast tanh, ~3 ulp, branch-free: only lane 0 (2x per wave per step).
// Output is always finite/non-NaN -> can never alias SENT.
__device__ __forceinline__ float fast_tanh(float x) {
  float xc = fminf(fmaxf(x, -9.0f), 9.0f);
  float e  = __expf(2.0f * xc);
  return (e - 1.0f) * __frcp_rn(e + 1.0f);
}

// Poll this thread's 4 records of one slot until non-sentinel, then deposit
// into LDS. Pending-only guarded loads (R1-best structure, measured fastest:
// done records generate ZERO further traffic).
__device__ __forceinline__ void poll_stage(const u32* rec, float* lds, int tid) {
  u32 v0 = SENT, v1 = SENT, v2 = SENT, v3 = SENT;
  bool d0 = false, d1 = false, d2 = false, d3 = false;
  for (;;) {
    if (!d0) { v0 = ld_rec(rec + tid           ); d0 = (v0 != SENT); }
    if (!d1) { v1 = ld_rec(rec + tid +     NTHR); d1 = (v1 != SENT); }
    if (!d2) { v2 = ld_rec(rec + tid + 2 * NTHR); d2 = (v2 != SENT); }
    if (!d3) { v3 = ld_rec(rec + tid + 3 * NTHR); d3 = (v3 != SENT); }
    if (d0 & d1 & d2 & d3) break;
    __builtin_amdgcn_s_sleep(1);
  }
  lds[tid           ] = __uint_as_float(v0);
  lds[tid +     NTHR] = __uint_as_float(v1);
  lds[tid + 2 * NTHR] = __uint_as_float(v2);
  lds[tid + 3 * NTHR] = __uint_as_float(v3);
}

// Dual-slot variant (h2 chain: h1[t] and h2[t-1]) — keeps one observe-RT
// per step with all pending loads in flight together.
__device__ __forceinline__ void poll_stage2(const u32* recA, const u32* recB,
                                            float* ldsA, float* ldsB, int tid) {
  u32 a0 = SENT, a1 = SENT, a2 = SENT, a3 = SENT;
  u32 b0 = SENT, b1 = SENT, b2 = SENT, b3 = SENT;
  bool da0 = false, da1 = false, da2 = false, da3 = false;
  bool db0 = false, db1 = false, db2 = false, db3 = false;
  for (;;) {
    if (!da0) { a0 = ld_rec(recA + tid           ); da0 = (a0 != SENT); }
    if (!da1) { a1 = ld_rec(recA + tid +     NTHR); da1 = (a1 != SENT); }
    if (!da2) { a2 = ld_rec(recA + tid + 2 * NTHR); da2 = (a2 != SENT); }
    if (!da3) { a3 = ld_rec(recA + tid + 3 * NTHR); da3 = (a3 != SENT); }
    if (!db0) { b0 = ld_rec(recB + tid           ); db0 = (b0 != SENT); }
    if (!db1) { b1 = ld_rec(recB + tid +     NTHR); db1 = (b1 != SENT); }
    if (!db2) { b2 = ld_rec(recB + tid + 2 * NTHR); db2 = (b2 != SENT); }
    if (!db3) { b3 = ld_rec(recB + tid + 3 * NTHR); db3 = (b3 != SENT); }
    if (da0 & da1 & da2 & da3 & db0 & db1 & db2 & db3) break;
    __builtin_amdgcn_s_sleep(1);
  }
  ldsA[tid           ] = __uint_as_float(a0);
  ldsA[tid +     NTHR] = __uint_as_float(a1);
  ldsA[tid + 2 * NTHR] = __uint_as_float(a2);
  ldsA[tid + 3 * NTHR] = __uint_as_float(a3);
  ldsB[tid           ] = __uint_as_float(b0);
  ldsB[tid +     NTHR] = __uint_as_float(b1);
  ldsB[tid + 2 * NTHR] = __uint_as_float(b2);
  ldsB[tid + 3 * NTHR] = __uint_as_float(b3);
}

// Sentinel-fill all records before each run (agent-scope stores: must be
// visible to the main kernel's L2-bypassing poll loads).
__global__ void init_kernel() {
  int i = blockIdx.x * blockDim.x + threadIdx.x;
  int n = gridDim.x * blockDim.x;
  for (int k = i; k < NSLOT * DH; k += n) {
    st_rec(&gR1[k], SENT);
    st_rec(&gR2[k], SENT);
  }
}

__global__ __launch_bounds__(NTHR, 2)
void rnn2_kernel(const float* __restrict__ X,
                 const float* __restrict__ Wa, const float* __restrict__ ba,
                 const float* __restrict__ Wb, const float* __restrict__ bb,
                 const float* __restrict__ Wc, const float* __restrict__ bc,
                 const float* __restrict__ Wd, const float* __restrict__ bd,
                 const float* __restrict__ Wo, const float* __restrict__ bo,
                 float* __restrict__ out)
{
  const int g   = blockIdx.x;
  const int tid = threadIdx.x;
  const int w   = tid >> 6;   // wave
  const int l   = tid & 63;   // lane

  // Double-buffered staging: stage(t) writes parity (t-1)&1 [h1] / t&1 [h2];
  // one barrier per step between stage and dot bounds wave skew -> reuse of
  // a parity buffer two steps later is race-free.
  __shared__ float sA[2][DH];
  __shared__ float sB[2][DH];

  if (g < HALF) {
    // ================= h1 chain (+ output epilogue) =================
    const int r0 = g * 16 + 2 * w, r1 = r0 + 1;   // my two h1 rows
    float4 wA0[4], wA1[4], wB0[8], wB1[8], wO[8];
    {
      const float4* p0 = (const float4*)(Wa + (size_t)r0 * DIN);
      const float4* p1 = (const float4*)(Wa + (size_t)r1 * DIN);
      #pragma unroll
      for (int j = 0; j < 4; ++j) { wA0[j] = p0[l + 64 * j]; wA1[j] = p1[l + 64 * j]; }
    }
    {
      const float4* p0 = (const float4*)(Wb + (size_t)r0 * DH);
      const float4* p1 = (const float4*)(Wb + (size_t)r1 * DH);
      #pragma unroll
      for (int j = 0; j < 8; ++j) { wB0[j] = p0[l + 64 * j]; wB1[j] = p1[l + 64 * j]; }
    }
    const int orow = g * 8 + w;                   // my output row
    {
      const float4* p = (const float4*)(Wo + (size_t)orow * DH);
      #pragma unroll
      for (int j = 0; j < 8; ++j) wO[j] = p[l + 64 * j];
    }
    const float b1_0 = ba[r0] + bb[r0];
    const float b1_1 = ba[r1] + bb[r1];
    const float bo_r = bo[orow];

    for (int t = 1; t <= TT; ++t) {
      // A.x[t-1]: no cross-WG dependency — compute before the wait
      float a0 = 0.f, a1 = 0.f;
      {
        const float4* px = (const float4*)(X + (size_t)(t - 1) * DIN);
        #pragma unroll
        for (int j = 0; j < 4; ++j) {
          float4 x4 = px[l + 64 * j];
          a0 += dot4(wA0[j], x4);
          a1 += dot4(wA1[j], x4);
        }
      }
      if (t > 1) {
        float* buf = sA[(t - 1) & 1];
        poll_stage(gR1 + (size_t)(t - 1) * DH, buf, tid);
        __syncthreads();
        const float4* ph = (const float4*)buf;
        #pragma unroll
        for (int j = 0; j < 8; ++j) {
          float4 h4 = ph[l + 64 * j];
          a0 += dot4(wB0[j], h4);
          a1 += dot4(wB1[j], h4);
        }
      }
      a0 = wave_sum(a0); a1 = wave_sum(a1);
      if (l == 0) {   // publish: two fire-and-forget atomic u32 records
        u32* dst = gR1 + (size_t)t * DH;
        st_rec(dst + r0, __float_as_uint(fast_tanh(a0 + b1_0)));
        st_rec(dst + r1, __float_as_uint(fast_tanh(a1 + b1_1)));
      }
    }

    // ---- epilogue: out = Wo . h2[TT] + bo (1 row per wave) ----
    // sA[0] parity != the loop's last dot buffer (sA[1]) -> race-free.
    poll_stage(gR2 + (size_t)TT * DH, sA[0], tid);
    __syncthreads();
    {
      const float4* ph = (const float4*)sA[0];
      float acc = 0.f;
      #pragma unroll
      for (int j = 0; j < 8; ++j) acc += dot4(wO[j], ph[l + 64 * j]);
      acc = wave_sum(acc);
      if (l == 0) out[orow] = acc + bo_r;
    }
  } else {
    // ========================= h2 chain =========================
    const int gg = g - HALF;
    const int r0 = gg * 16 + 2 * w, r1 = r0 + 1;  // my two h2 rows
    float4 wC0[8], wC1[8], wD0[8], wD1[8];
    {
      const float4* p0 = (const float4*)(Wc + (size_t)r0 * DH);
      const float4* p1 = (const float4*)(Wc + (size_t)r1 * DH);
      #pragma unroll
      for (int j = 0; j < 8; ++j) { wC0[j] = p0[l + 64 * j]; wC1[j] = p1[l + 64 * j]; }
    }
    {
      const float4* p0 = (const float4*)(Wd + (size_t)r0 * DH);
      const float4* p1 = (const float4*)(Wd + (size_t)r1 * DH);
      #pragma unroll
      for (int j = 0; j < 8; ++j) { wD0[j] = p0[l + 64 * j]; wD1[j] = p1[l + 64 * j]; }
    }
    const float b2_0 = bc[r0] + bd[r0];
    const float b2_1 = bc[r1] + bd[r1];

    for (int t = 1; t <= TT; ++t) {
      float* bufA = sA[t & 1];
      float* bufB = sB[t & 1];
      if (t > 1)
        poll_stage2(gR1 + (size_t)t * DH,
                    gR2 + (size_t)(t - 1) * DH, bufA, bufB, tid);
      else
        poll_stage(gR1 + (size_t)1 * DH, bufA, tid);
      __syncthreads();

      float a0 = 0.f, a1 = 0.f;
      {
        const float4* ph = (const float4*)bufA;
        #pragma unroll
        for (int j = 0; j < 8; ++j) {
          float4 h4 = ph[l + 64 * j];
          a0 += dot4(wC0[j], h4);
          a1 += dot4(wC1[j], h4);
        }
      }
      if (t > 1) {
        const float4* ph = (const float4*)bufB;
        #pragma unroll
        for (int j = 0; j < 8; ++j) {
          float4 h4 = ph[l + 64 * j];
          a0 += dot4(wD0[j], h4);
          a1 += dot4(wD1[j], h4);
        }
      }
      a0 = wave_sum(a0); a1 = wave_sum(a1);
      if (l == 0) {
        u32* dst = gR2 + (size_t)t * DH;
        st_rec(dst + r0, __float_as_uint(fast_tanh(a0 + b2_0)));
        st_rec(dst + r1, __float_as_uint(fast_tanh(a1 + b2_1)));
      }
    }
  }
}

extern "C" void kernel_launch(void* const* d_in, const int* in_sizes, int n_in,
                              void* d_out, int out_size, void* d_ws, size_t ws_size,
                              hipStream_t stream)
{
  (void)in_sizes; (void)n_in; (void)out_size; (void)d_ws; (void)ws_size;

  const float* X  = (const float*)d_in[0];
  const float* Wa = (const float*)d_in[1];   // W_i2h1 [H][IN]
  const float* ba = (const float*)d_in[2];
  const float* Wb = (const float*)d_in[3];   // W_h2h1 [H][H]
  const float* bb = (const float*)d_in[4];
  // d_in[5], d_in[6]: W_h2o1 / b_h2o1 — dead code in the reference
  const float* Wc = (const float*)d_in[7];   // W_i2h2 [H][H]
  const float* bc = (const float*)d_in[8];
  const float* Wd = (const float*)d_in[9];   // W_h2h2 [H][H]
  const float* bd = (const float*)d_in[10];
  const float* Wo = (const float*)d_in[11];  // W_h2o2 [OUT][H]
  const float* bo = (const float*)d_in[12];
  float* out = (float*)d_out;

  init_kernel<<<dim3(1024), dim3(256), 0, stream>>>();

  void* args[] = { &X, &Wa, &ba, &Wb, &bb, &Wc, &bc, &Wd, &bd, &Wo, &bo, &out };
  (void)hipLaunchCooperativeKernel((void*)rnn2_kernel, dim3(NWG), dim3(NTHR),
                                   args, 0, stream);
}